// Round 2
// baseline (347.196 us; speedup 1.0000x reference)
//
#include <hip/hip_runtime.h>
#include <hip/hip_bf16.h>

// Problem constants (from reference): B=4, F=8, C=16, H=256, W=256, K=64
#define NB 4
#define NF 8
#define NC 16
#define NK 64
#define HW 65536              // H*W
#define NBF 32                // B*F
#define BPF 32                // blocks per frame
#define PPB (HW / BPF)        // pixels per block = 2048

__global__ __launch_bounds__(256) void zero_kernel(float* __restrict__ p, int n) {
    int i = blockIdx.x * blockDim.x + threadIdx.x;
    if (i < n) p[i] = 0.0f;
}

// Each block: one 2048-pixel chunk of one (b,f) frame.
// LDS accumulator laid out [c][k] so random ids hit bank id%32 (all 32 banks).
__global__ __launch_bounds__(256) void accum_kernel(const float* __restrict__ E,
                                                    const int* __restrict__ T,
                                                    float* __restrict__ gsum,   // [bf][k][c]
                                                    float* __restrict__ gcnt) { // [bf][k]
    __shared__ float ls[NC * NK];   // [c][k]
    __shared__ float lc[NK];
    const int tid = threadIdx.x;

    for (int i = tid; i < NC * NK; i += 256) ls[i] = 0.0f;
    if (tid < NK) lc[tid] = 0.0f;
    __syncthreads();

    const int bf    = blockIdx.x / BPF;
    const int chunk = blockIdx.x % BPF;
    const int* __restrict__ Tp = T + (size_t)bf * HW + chunk * PPB;
    const float* __restrict__ Ep = E + (size_t)bf * NC * HW + chunk * PPB;

    #pragma unroll
    for (int it = 0; it < PPB / 1024; ++it) {       // 2 iters; 256 thr * 4 px
        const int p = it * 1024 + tid * 4;
        const int4 id4 = *reinterpret_cast<const int4*>(Tp + p);
        atomicAdd(&lc[id4.x], 1.0f);
        atomicAdd(&lc[id4.y], 1.0f);
        atomicAdd(&lc[id4.z], 1.0f);
        atomicAdd(&lc[id4.w], 1.0f);
        #pragma unroll
        for (int c = 0; c < NC; ++c) {
            const float4 v = *reinterpret_cast<const float4*>(Ep + (size_t)c * HW + p);
            atomicAdd(&ls[c * NK + id4.x], v.x);
            atomicAdd(&ls[c * NK + id4.y], v.y);
            atomicAdd(&ls[c * NK + id4.z], v.z);
            atomicAdd(&ls[c * NK + id4.w], v.w);
        }
    }
    __syncthreads();

    // Flush LDS [c][k] -> global [bf][k][c]
    for (int i = tid; i < NC * NK; i += 256) {
        const int c = i >> 6;         // i / 64
        const int k = i & 63;         // i % 64
        atomicAdd(&gsum[(size_t)bf * (NK * NC) + k * NC + c], ls[i]);
    }
    if (tid < NK) atomicAdd(&gcnt[(size_t)bf * NK + tid], lc[tid]);
}

// Single block: 4*7*64 = 1792 (b, f-pair, k) combos, reduce to scalar.
__global__ __launch_bounds__(256) void finish_kernel(const float* __restrict__ gsum,
                                                     const float* __restrict__ gcnt,
                                                     float* __restrict__ out) {
    float total = 0.0f, nv = 0.0f;
    for (int idx = threadIdx.x; idx < NB * (NF - 1) * NK; idx += 256) {
        const int k = idx & 63;
        const int bfr = idx >> 6;          // 0..27 = b*(F-1)+f
        const int b = bfr / (NF - 1);
        const int f = bfr % (NF - 1);
        const int bf0 = b * NF + f;
        if (k == 0) continue;
        const float c0 = gcnt[bf0 * NK + k];
        const float c1 = gcnt[(bf0 + 1) * NK + k];
        if (c0 > 0.0f && c1 > 0.0f) {
            const float r0 = 1.0f / c0, r1 = 1.0f / c1;
            float d = 0.0f;
            #pragma unroll
            for (int c = 0; c < NC; ++c) {
                const float m0 = gsum[(size_t)bf0 * (NK * NC) + k * NC + c] * r0;
                const float m1 = gsum[(size_t)(bf0 + 1) * (NK * NC) + k * NC + c] * r1;
                const float df = m0 - m1;
                d += df * df;
            }
            total += d;
            nv += 1.0f;
        }
    }
    // block reduce: 4 waves of 64
    const int lane = threadIdx.x & 63;
    const int wv   = threadIdx.x >> 6;
    #pragma unroll
    for (int off = 32; off > 0; off >>= 1) {
        total += __shfl_down(total, off, 64);
        nv    += __shfl_down(nv, off, 64);
    }
    __shared__ float sT[4], sN[4];
    if (lane == 0) { sT[wv] = total; sN[wv] = nv; }
    __syncthreads();
    if (threadIdx.x == 0) {
        const float t = sT[0] + sT[1] + sT[2] + sT[3];
        const float n = sN[0] + sN[1] + sN[2] + sN[3];
        out[0] = (n > 0.0f) ? (t / n) : 0.0f;
    }
}

extern "C" void kernel_launch(void* const* d_in, const int* in_sizes, int n_in,
                              void* d_out, int out_size, void* d_ws, size_t ws_size,
                              hipStream_t stream) {
    const float* E = (const float*)d_in[0];   // embeddings (4,8,16,256,256) f32
    const int*   T = (const int*)d_in[1];     // track_ids  (4,8,1,256,256) i32
    float* out = (float*)d_out;

    float* gsum = (float*)d_ws;               // [32][64][16] = 32768 floats
    float* gcnt = gsum + NBF * NK * NC;       // [32][64]     = 2048 floats
    const int ntot = NBF * NK * NC + NBF * NK; // 34816

    zero_kernel<<<(ntot + 255) / 256, 256, 0, stream>>>(gsum, ntot);
    accum_kernel<<<NBF * BPF, 256, 0, stream>>>(E, T, gsum, gcnt);
    finish_kernel<<<1, 256, 0, stream>>>(gsum, gcnt, out);
}

// Round 3
// 223.201 us; speedup vs baseline: 1.5555x; 1.5555x over previous
//
#include <hip/hip_runtime.h>
#include <hip/hip_bf16.h>

// Problem constants: B=4, F=8, C=16, H=256, W=256, K=64
#define NB 4
#define NF 8
#define NC 16
#define NK 64
#define HW 65536              // H*W
#define NBF 32                // B*F
#define BPF 16                // blocks per frame
#define PPB (HW / BPF)        // 4096 pixels per block
#define PPW (PPB / 4)         // 1024 pixels per wave
#define STEPS (PPW / 32)      // 32 K-steps of 32 pixels

typedef __attribute__((ext_vector_type(8))) short bf16x8;  // MFMA A/B frag (8 bf16)
typedef __attribute__((ext_vector_type(4))) float f32x4;   // MFMA C/D frag

__global__ __launch_bounds__(256) void zero_kernel(float* __restrict__ p, int n) {
    int i = blockIdx.x * blockDim.x + threadIdx.x;
    if (i < n) p[i] = 0.0f;
}

__device__ __forceinline__ short f32_to_bf16_bits(float x) {
    union { float f; unsigned u; } v; v.f = x;
    unsigned r = v.u + 0x7FFFu + ((v.u >> 16) & 1u);   // round-nearest-even
    return (short)(r >> 16);
}

// Segment-sum via one-hot MFMA. Per wave: 32-pixel K-steps.
//   A (16x32, bf16): onehot[k - 16t][p]; rows = lane&15, k-slots = mirrored with B.
//   B (32x16, bf16): data[p][c]; cols = lane&15 (channel plane), 8 consecutive pixels/lane.
//   C/D layout (verified m89/m91): col = lane&15, row = (lane>>4)*4 + reg.
__global__ __launch_bounds__(256) void accum_mfma(const float* __restrict__ E,
                                                  const int* __restrict__ T,
                                                  float* __restrict__ gsum,   // [bf][k][c]
                                                  float* __restrict__ gcnt) { // [bf][k]
    const int tid = threadIdx.x;
    const int wv  = tid >> 6;
    const int l   = tid & 63;
    const int col = l & 15;    // channel (B/C col) AND A row-within-tile
    const int grp = l >> 4;    // pixel-slot group

    const int bf    = blockIdx.x / BPF;
    const int chunk = blockIdx.x % BPF;
    const int base  = chunk * PPB + wv * PPW + grp * 8;

    const int*   Tp = T + (size_t)bf * HW + base;
    const float* Ep = E + ((size_t)bf * NC + col) * HW + base;

    f32x4 accS[4], accC[4];
    #pragma unroll
    for (int t = 0; t < 4; ++t) { accS[t] = (f32x4){0,0,0,0}; accC[t] = (f32x4){0,0,0,0}; }

    // Constant ones-fragment: B[p][0] = 1.0 for all p -> counts in col 0.
    bf16x8 bOnes;
    {
        const short ov = (col == 0) ? (short)0x3F80 : (short)0;
        #pragma unroll
        for (int j = 0; j < 8; ++j) bOnes[j] = ov;
    }

    for (int s = 0; s < STEPS; ++s) {
        const int off = s * 32;
        const int4   i0 = *reinterpret_cast<const int4*>(Tp + off);
        const int4   i1 = *reinterpret_cast<const int4*>(Tp + off + 4);
        const float4 d0 = *reinterpret_cast<const float4*>(Ep + off);
        const float4 d1 = *reinterpret_cast<const float4*>(Ep + off + 4);

        const int   idv[8] = {i0.x, i0.y, i0.z, i0.w, i1.x, i1.y, i1.z, i1.w};
        const float dv[8]  = {d0.x, d0.y, d0.z, d0.w, d1.x, d1.y, d1.z, d1.w};

        bf16x8 bF;
        #pragma unroll
        for (int j = 0; j < 8; ++j) bF[j] = f32_to_bf16_bits(dv[j]);

        #pragma unroll
        for (int t = 0; t < 4; ++t) {
            const int ktar = t * 16 + col;
            bf16x8 aT;
            #pragma unroll
            for (int j = 0; j < 8; ++j) aT[j] = (idv[j] == ktar) ? (short)0x3F80 : (short)0;
            accS[t] = __builtin_amdgcn_mfma_f32_16x16x32_bf16(aT, bF,    accS[t], 0, 0, 0);
            accC[t] = __builtin_amdgcn_mfma_f32_16x16x32_bf16(aT, bOnes, accC[t], 0, 0, 0);
        }
    }

    // Cross-wave reduce in LDS, then one global atomic per output element.
    __shared__ float lsum[4][NK][NC];   // 16 KiB
    __shared__ float lcnt[4][NK];       // 1 KiB
    #pragma unroll
    for (int t = 0; t < 4; ++t) {
        #pragma unroll
        for (int j = 0; j < 4; ++j) {
            const int k = t * 16 + grp * 4 + j;   // C/D row mapping (m89)
            lsum[wv][k][col] = accS[t][j];
            if (col == 0) lcnt[wv][k] = accC[t][j];
        }
    }
    __syncthreads();

    float* gs = gsum + (size_t)bf * NK * NC;
    const float* lp = &lsum[0][0][0];
    for (int i = tid; i < NK * NC; i += 256) {
        atomicAdd(&gs[i], lp[i] + lp[NK*NC + i] + lp[2*NK*NC + i] + lp[3*NK*NC + i]);
    }
    if (tid < NK) {
        atomicAdd(&gcnt[(size_t)bf * NK + tid],
                  lcnt[0][tid] + lcnt[1][tid] + lcnt[2][tid] + lcnt[3][tid]);
    }
}

// Single block: 4*7*64 = 1792 (b, f-pair, k) combos, reduce to scalar.
__global__ __launch_bounds__(256) void finish_kernel(const float* __restrict__ gsum,
                                                     const float* __restrict__ gcnt,
                                                     float* __restrict__ out) {
    float total = 0.0f, nv = 0.0f;
    for (int idx = threadIdx.x; idx < NB * (NF - 1) * NK; idx += 256) {
        const int k = idx & 63;
        const int bfr = idx >> 6;
        const int b = bfr / (NF - 1);
        const int f = bfr % (NF - 1);
        const int bf0 = b * NF + f;
        if (k == 0) continue;
        const float c0 = gcnt[bf0 * NK + k];
        const float c1 = gcnt[(bf0 + 1) * NK + k];
        if (c0 > 0.0f && c1 > 0.0f) {
            const float r0 = 1.0f / c0, r1 = 1.0f / c1;
            float d = 0.0f;
            #pragma unroll
            for (int c = 0; c < NC; ++c) {
                const float m0 = gsum[(size_t)bf0 * (NK * NC) + k * NC + c] * r0;
                const float m1 = gsum[(size_t)(bf0 + 1) * (NK * NC) + k * NC + c] * r1;
                const float df = m0 - m1;
                d += df * df;
            }
            total += d;
            nv += 1.0f;
        }
    }
    const int lane = threadIdx.x & 63;
    const int wvi  = threadIdx.x >> 6;
    #pragma unroll
    for (int off = 32; off > 0; off >>= 1) {
        total += __shfl_down(total, off, 64);
        nv    += __shfl_down(nv, off, 64);
    }
    __shared__ float sT[4], sN[4];
    if (lane == 0) { sT[wvi] = total; sN[wvi] = nv; }
    __syncthreads();
    if (threadIdx.x == 0) {
        const float t = sT[0] + sT[1] + sT[2] + sT[3];
        const float n = sN[0] + sN[1] + sN[2] + sN[3];
        out[0] = (n > 0.0f) ? (t / n) : 0.0f;
    }
}

extern "C" void kernel_launch(void* const* d_in, const int* in_sizes, int n_in,
                              void* d_out, int out_size, void* d_ws, size_t ws_size,
                              hipStream_t stream) {
    const float* E = (const float*)d_in[0];   // embeddings (4,8,16,256,256) f32
    const int*   T = (const int*)d_in[1];     // track_ids  (4,8,1,256,256) i32
    float* out = (float*)d_out;

    float* gsum = (float*)d_ws;               // [32][64][16]
    float* gcnt = gsum + NBF * NK * NC;       // [32][64]
    const int ntot = NBF * NK * NC + NBF * NK;

    zero_kernel<<<(ntot + 255) / 256, 256, 0, stream>>>(gsum, ntot);
    accum_mfma<<<NBF * BPF, 256, 0, stream>>>(E, T, gsum, gcnt);
    finish_kernel<<<1, 256, 0, stream>>>(gsum, gcnt, out);
}